// Round 12
// baseline (598.280 us; speedup 1.0000x reference)
//
#include <hip/hip_runtime.h>
#include <hip/hip_bf16.h>
#include <hip/hip_fp16.h>

#define VOCAB 32000
#define H 256
#define B 4
#define S 512

typedef _Float16 f16x8 __attribute__((ext_vector_type(8)));
typedef short s16x8 __attribute__((ext_vector_type(8)));
typedef float f32x4 __attribute__((ext_vector_type(4)));

__device__ __forceinline__ float tanh_fast(float x) {
    float e = exp2f(x * 2.885390081777927f);   // exp(2x)
    return 1.0f - 2.0f * __builtin_amdgcn_rcpf(e + 1.0f);
}

// Fragment-major index (A-operand view), KK=8 (K=256)
__device__ __forceinline__ size_t fragIdx(int row, int h) {
    return ((size_t)((((row >> 4) * 8 + (h >> 5)) * 64) + ((h >> 3) & 3) * 16 + (row & 15)) << 3)
           + (h & 7);
}

// ---------------------------------------------------------------------------
// K_PREP: blocks 0..511 = eprep; blocks 512..2511 = Wo->WoTF (64n x 64k tiles,
// 16.6KB LDS). Unchanged from R11 (banked −7us vs separate launches).
// ---------------------------------------------------------------------------
__global__ __launch_bounds__(256) void k_prep(const int* __restrict__ x,
                                              const float* __restrict__ embed,
                                              const float* __restrict__ Wi,
                                              const float* __restrict__ bi,
                                              const float* __restrict__ bh,
                                              float* __restrict__ Ew,
                                              const float* __restrict__ Wo,
                                              ushort* __restrict__ WoTF) {
    __shared__ float sm[64 * 65 + 8];
    int tid = threadIdx.x;
    if (blockIdx.x < S) {
        float (*es)[H] = (float(*)[H])sm;
        int* xs = (int*)&sm[B * H];
        int t = blockIdx.x, j = tid;
        if (j < B) xs[j] = x[j * S + t];
        __syncthreads();
        for (int b = 0; b < B; ++b) es[b][j] = embed[(size_t)xs[b] * H + j];
        float bias = bi[j] + bh[j];
        float a0 = bias, a1 = bias, a2 = bias, a3 = bias;
        __syncthreads();
        for (int i = 0; i < H; ++i) {
            float w = Wi[i * H + j];
            a0 += es[0][i] * w; a1 += es[1][i] * w;
            a2 += es[2][i] * w; a3 += es[3][i] * w;
        }
        f32x4 v; v[0] = a0; v[1] = a1; v[2] = a2; v[3] = a3;
        *(f32x4*)&Ew[(t * H + j) * 4] = v;
    } else {
        float (*tile)[65] = (float(*)[65])sm;
        int bid2 = blockIdx.x - S;
        int n0 = (bid2 % 500) * 64;
        int k0 = (bid2 / 500) * 64;
        int tx = tid & 63, ty = tid >> 6;
#pragma unroll
        for (int i = 0; i < 16; ++i) {
            int kr = i * 4 + ty;
            tile[kr][tx] = Wo[(size_t)(k0 + kr) * VOCAB + n0 + tx];
        }
        __syncthreads();
#pragma unroll
        for (int r = 0; r < 2; ++r) {
            int lin = tid + 256 * r;
            int ll = lin & 15, lg = (lin >> 4) & 3, kkL = (lin >> 6) & 1, nt = (lin >> 7) & 3;
            int kk = (k0 >> 5) + kkL;
            int n = nt * 16 + ll;
            s16x8 v;
#pragma unroll
            for (int e = 0; e < 8; ++e) {
                __hip_bfloat16 b = __float2bfloat16(tile[kkL * 32 + lg * 8 + e][n]);
                v[e] = *(short*)&b;
            }
            size_t unit = (size_t)(((n0 >> 4) + nt) * 8 + kk) * 64 + lg * 16 + ll;
            *(s16x8*)&WoTF[unit * 8] = v;
        }
    }
}

// ---------------------------------------------------------------------------
// K2 v9: serial RNN scan, 8 WAVES (512 threads), 2 waves/SIMD.
// Theory: at 1 wave/SIMD every serial latency (ds_read ~120cy, tanh trans,
// store issue) is exposed; 2 waves/SIMD lets wave A's latency hide under
// wave B's MFMA. Each wave owns 2 n-tiles (32 cols): 16 MFMA/wave/step,
// total 128/step unchanged. Cost: 2x LDS read traffic (each wave still
// needs full K=256 of h). Extra trick: lane-groups 2-3 (replica rows) do
// the enc16 GLOBAL stores; lane-groups 0-1 do only the LDS write ->
// global stores leave the hbuf->barrier critical path.
// Body otherwise identical to R7-best (pitch-258, static select, depth-2
// Ew prefetch, 1 barrier/step).
// ---------------------------------------------------------------------------
__global__ __launch_bounds__(512, 1) void k_rnn(const float* __restrict__ Ew,
                                                const float* __restrict__ Wh,
                                                _Float16* __restrict__ enc16,
                                                float* __restrict__ out_tail) {
    const int tid = threadIdx.x;
    const int w = tid >> 6;          // wave 0..7: owns cols w*32 .. w*32+31
    const int l = tid & 63;
    const int lg = l >> 4;
    const int ll = l & 15;

    __shared__ _Float16 hbuf[2][4][258];
    for (int idx = tid; idx < 2 * 4 * 258; idx += 512) (&hbuf[0][0][0])[idx] = (_Float16)0.f;

    // Wh B-fragments: wave w, tile nt -> cols w*32 + nt*16 + ll
    f16x8 Bf[2][8];
#pragma unroll
    for (int nt = 0; nt < 2; ++nt) {
        int col = w * 32 + nt * 16 + ll;
#pragma unroll
        for (int kk = 0; kk < 8; ++kk) {
            int kb = kk * 32 + lg * 8;
            f16x8 v;
#pragma unroll
            for (int e = 0; e < 8; ++e) v[e] = (_Float16)Wh[(kb + e) * H + col];
            Bf[nt][kk] = v;
        }
    }
    __syncthreads();

    f32x4 eacc[2][2];
#pragma unroll
    for (int d = 0; d < 2; ++d)
#pragma unroll
        for (int nt = 0; nt < 2; ++nt) {
            int j = w * 32 + nt * 16 + ll;
            eacc[d][nt] = *(const f32x4*)&Ew[(d * H + j) * 4];
        }

    const int jcol = w * 32 + (lg & 1) * 16 + ll;   // col this lane finalizes

    for (int t0 = 0; t0 < S; t0 += 2) {
#pragma unroll
        for (int u = 0; u < 2; ++u) {
            const int t = t0 + u;
            const int cur = u, nxt = u ^ 1;

            f16x8 Af[8];
#pragma unroll
            for (int kk = 0; kk < 8; ++kk)
                Af[kk] = *(const f16x8*)&hbuf[cur][l & 3][kk * 32 + lg * 8];

            f32x4 acc[2];
#pragma unroll
            for (int nt = 0; nt < 2; ++nt) acc[nt] = eacc[u][nt];

            {
                int tp = (t + 2 < S) ? t + 2 : S - 1;
#pragma unroll
                for (int nt = 0; nt < 2; ++nt) {
                    int j = w * 32 + nt * 16 + ll;
                    eacc[u][nt] = *(const f32x4*)&Ew[(tp * H + j) * 4];
                }
            }

#pragma unroll
            for (int kk = 0; kk < 8; ++kk)
#pragma unroll
                for (int nt = 0; nt < 2; ++nt)
                    acc[nt] = __builtin_amdgcn_mfma_f32_16x16x32_f16(Af[kk], Bf[nt][kk], acc[nt], 0, 0, 0);

            // D rows 4-15 are valid batch replicas: acc[nt][r] at lane (lg,ll)
            // is h_next[r][w*32 + nt*16 + ll] for every lg. Lane-group split:
            // lg 0,1 -> LDS write (critical path); lg 2,3 -> global stores.
            float v[4];
#pragma unroll
            for (int r = 0; r < 4; ++r) v[r] = (lg & 1) ? acc[1][r] : acc[0][r];

            _Float16 h16[4];
#pragma unroll
            for (int r = 0; r < 4; ++r) h16[r] = (_Float16)tanh_fast(v[r]);

            if (lg < 2) {
#pragma unroll
                for (int r = 0; r < 4; ++r) hbuf[nxt][r][jcol] = h16[r];
                if (t == S - 1) {
#pragma unroll
                    for (int r = 0; r < 4; ++r) out_tail[r * H + jcol] = tanh_fast(v[r]);
                }
            } else {
#pragma unroll
                for (int r = 0; r < 4; ++r)
                    enc16[(r * S + t) * H + jcol] = h16[r];   // fire-and-forget
            }

            asm volatile("s_waitcnt lgkmcnt(0)" ::: "memory");
            __builtin_amdgcn_s_barrier();
            asm volatile("" ::: "memory");
        }
    }
}

// ---------------------------------------------------------------------------
// K3: q = enc@Wq ; kT = enc@Wk + ba ([b][h][s]); also emits encF (B-frag f16)
// ---------------------------------------------------------------------------
__global__ void k_qk(const _Float16* __restrict__ enc16, const float* __restrict__ Wa,
                     const float* __restrict__ ba, float* __restrict__ q,
                     float* __restrict__ kT, ushort* __restrict__ encF) {
    int r0 = blockIdx.x * 8;
    int j = threadIdx.x;
    __shared__ float es[8][H];
#pragma unroll
    for (int r = 0; r < 8; ++r) es[r][j] = (float)enc16[(r0 + r) * H + j];
    __syncthreads();
    float aq[8] = {0, 0, 0, 0, 0, 0, 0, 0};
    float ak[8] = {0, 0, 0, 0, 0, 0, 0, 0};
    for (int i = 0; i < H; ++i) {
        float wq = Wa[i * H + j];
        float wk = Wa[(H + i) * H + j];
#pragma unroll
        for (int r = 0; r < 8; ++r) { aq[r] += es[r][i] * wq; ak[r] += es[r][i] * wk; }
    }
    float bav = ba[j];
#pragma unroll
    for (int r = 0; r < 8; ++r) {
        int row = r0 + r;
        int b = row >> 9, t = row & (S - 1);
        q[row * H + j] = aq[r];
        kT[((b * H + j) << 9) + t] = ak[r] + bav;
        _Float16 ev = (_Float16)es[r][j];
        size_t unit = (size_t)((b * 16 + (j >> 4)) * 16 + (t >> 5)) * 64 + ((t >> 3) & 3) * 16 + (j & 15);
        encF[unit * 8 + (t & 7)] = *(ushort*)&ev;
    }
}

// ---------------------------------------------------------------------------
// K4: scores -> fixed-max softmax -> normalized f16 weights, A-frag-major.
// ---------------------------------------------------------------------------
__global__ void k_attn(const float* __restrict__ q, const float* __restrict__ kT,
                       const float* __restrict__ va, ushort* __restrict__ WgtF) {
    int bt = blockIdx.x;
    int b = bt >> 9, t = bt & (S - 1);
    int tid = threadIdx.x;
    if (t == 0) {
        for (int ss = tid; ss < S; ss += 256) {
            _Float16 hw = (_Float16)((ss == 0) ? 1.f : 0.f);
            size_t unit = (size_t)((b * 32 + (t >> 4)) * 16 + (ss >> 5)) * 64 + ((ss >> 3) & 3) * 16 + (t & 15);
            WgtF[unit * 8 + (ss & 7)] = *(ushort*)&hw;
        }
        return;
    }
    __shared__ float qs[H], vas[H], part[4][S], wgt[S], red[4];
    qs[tid] = q[bt * H + tid];
    vas[tid] = va[tid];
    __syncthreads();

    int sl = tid & 63, g = tid >> 6;
    int nchunk = (t + 63) >> 6;
    const float* kTb = kT + ((size_t)(b * H) << 9);
    for (int c = 0; c < nchunk; ++c) {
        int s = c * 64 + sl;
        float p = 0.f;
        if (s < t) {
            int hb = g * 64;
            for (int i = 0; i < 64; ++i) {
                int h = hb + i;
                p += vas[h] * tanh_fast(qs[h] + kTb[(h << 9) + s]);
            }
        }
        part[g][s] = p;
    }
    __syncthreads();

    float ssum = 0.f;
    for (int s = tid; s < t; s += 256) {
        float sc = part[0][s] + part[1][s] + part[2][s] + part[3][s];
        float e = exp2f((sc - 16.0f) * 1.4426950408889634f);
        wgt[s] = e;
        ssum += e;
    }
#pragma unroll
    for (int off = 32; off; off >>= 1) ssum += __shfl_xor(ssum, off);
    if ((tid & 63) == 0) red[g] = ssum;
    __syncthreads();
    float inv = 1.0f / (red[0] + red[1] + red[2] + red[3]);

    for (int ss = tid; ss < S; ss += 256) {
        float wv = (ss < t) ? wgt[ss] * inv : 0.f;
        _Float16 hw = (_Float16)wv;
        size_t unit = (size_t)((b * 32 + (t >> 4)) * 16 + (ss >> 5)) * 64 + ((ss >> 3) & 3) * 16 + (t & 15);
        WgtF[unit * 8 + (ss & 7)] = *(ushort*)&hw;
    }
}

// ---------------------------------------------------------------------------
// K_CTX: ctx = Wgt @ enc per batch (MFMA), + enc, -> AbfF fragment-major.
// R7 32-row version.
// ---------------------------------------------------------------------------
__global__ __launch_bounds__(256) void k_ctx(const ushort* __restrict__ WgtF,
                                             const ushort* __restrict__ encF,
                                             const _Float16* __restrict__ enc16,
                                             ushort* __restrict__ AbfF) {
    int b = blockIdx.y;
    int m0 = blockIdx.x * 32;
    int tid = threadIdx.x;
    int wv = tid >> 6, l = tid & 63;
    int lg = l >> 4, ll = l & 15;

    f32x4 acc[2][4];
#pragma unroll
    for (int mt = 0; mt < 2; ++mt)
#pragma unroll
        for (int nt = 0; nt < 4; ++nt) { f32x4 z; z[0]=0.f; z[1]=0.f; z[2]=0.f; z[3]=0.f; acc[mt][nt] = z; }

#pragma unroll
    for (int kk = 0; kk < 16; ++kk) {
        f16x8 a[2], bf[4];
#pragma unroll
        for (int mt = 0; mt < 2; ++mt)
            a[mt] = *(const f16x8*)&WgtF[((size_t)((b * 32 + (m0 >> 4) + mt) * 16 + kk) * 64 + l) * 8];
#pragma unroll
        for (int nt = 0; nt < 4; ++nt)
            bf[nt] = *(const f16x8*)&encF[((size_t)((b * 16 + wv * 4 + nt) * 16 + kk) * 64 + l) * 8];
#pragma unroll
        for (int mt = 0; mt < 2; ++mt)
#pragma unroll
            for (int nt = 0; nt < 4; ++nt)
                acc[mt][nt] = __builtin_amdgcn_mfma_f32_16x16x32_f16(a[mt], bf[nt], acc[mt][nt], 0, 0, 0);
    }

#pragma unroll
    for (int mt = 0; mt < 2; ++mt)
#pragma unroll
        for (int nt = 0; nt < 4; ++nt)
#pragma unroll
            for (int r = 0; r < 4; ++r) {
                int trow = m0 + mt * 16 + lg * 4 + r;
                int h = wv * 64 + nt * 16 + ll;
                float ev = (float)enc16[(size_t)(b * S + trow) * H + h];
                __hip_bfloat16 o = __float2bfloat16(acc[mt][nt][r] + ev);
                AbfF[fragIdx(b * S + trow, h)] = *(ushort*)&o;
            }
}

// ---------------------------------------------------------------------------
// K5: out = A @ WoT^T + bo. Fragment-major operands; m-fastest grid.
// ---------------------------------------------------------------------------
__global__ __launch_bounds__(256) void k_out(const ushort* __restrict__ AbfF,
                                             const ushort* __restrict__ WoTF,
                                             const float* __restrict__ bo,
                                             float* __restrict__ out) {
    int tid = threadIdx.x;
    int wv = tid >> 6, l = tid & 63;
    int mw = wv >> 1, nw = wv & 1;
    int lg = l >> 4, ll = l & 15;
    int m0 = blockIdx.x * 128 + mw * 64;
    int n0 = blockIdx.y * 128 + nw * 64;

    f32x4 acc[4][4];
#pragma unroll
    for (int mt = 0; mt < 4; ++mt)
#pragma unroll
        for (int nt = 0; nt < 4; ++nt) { f32x4 z; z[0]=0.f; z[1]=0.f; z[2]=0.f; z[3]=0.f; acc[mt][nt] = z; }

#pragma unroll
    for (int kk = 0; kk < 8; ++kk) {
        s16x8 a[4], bf[4];
#pragma unroll
        for (int mt = 0; mt < 4; ++mt)
            a[mt] = *(const s16x8*)&AbfF[((size_t)(((m0 >> 4) + mt) * 8 + kk) * 64 + l) * 8];
#pragma unroll
        for (int nt = 0; nt < 4; ++nt)
            bf[nt] = *(const s16x8*)&WoTF[((size_t)(((n0 >> 4) + nt) * 8 + kk) * 64 + l) * 8];
#pragma unroll
        for (int mt = 0; mt < 4; ++mt)
#pragma unroll
            for (int nt = 0; nt < 4; ++nt)
                acc[mt][nt] = __builtin_amdgcn_mfma_f32_16x16x32_bf16(a[mt], bf[nt], acc[mt][nt], 0, 0, 0);
    }

#pragma unroll
    for (int nt = 0; nt < 4; ++nt) {
        int n = n0 + nt * 16 + ll;
        float bov = bo[n];
#pragma unroll
        for (int mt = 0; mt < 4; ++mt) {
#pragma unroll
            for (int r = 0; r < 4; ++r) {
                int mrow = m0 + mt * 16 + lg * 4 + r;
                out[(size_t)mrow * VOCAB + n] = acc[mt][nt][r] + bov;
            }
        }
    }
}

// ---------------------------------------------------------------------------
extern "C" void kernel_launch(void* const* d_in, const int* in_sizes, int n_in,
                              void* d_out, int out_size, void* d_ws, size_t ws_size,
                              hipStream_t stream) {
    const int*   x     = (const int*)d_in[0];
    const float* embed = (const float*)d_in[1];
    const float* Wi    = (const float*)d_in[2];
    const float* bi    = (const float*)d_in[3];
    const float* Wh    = (const float*)d_in[4];
    const float* bh    = (const float*)d_in[5];
    const float* Wa    = (const float*)d_in[6];
    const float* ba    = (const float*)d_in[7];
    const float* va    = (const float*)d_in[8];
    const float* Wo    = (const float*)d_in[9];
    const float* bo    = (const float*)d_in[10];
    float* out = (float*)d_out;

    char* wsb = (char*)d_ws;
    float*    Ew    = (float*)(wsb);                  //  2 MB
    _Float16* enc16 = (_Float16*)(wsb + (2 << 20));   //  1 MB
    float*    q     = (float*)(wsb + (3 << 20));      //  2 MB
    float*    kT    = (float*)(wsb + (5 << 20));      //  2 MB
    ushort*   AbfF  = (ushort*)(wsb + (7 << 20));     //  1 MB  A fragment-major
    ushort*   WoTF  = (ushort*)(wsb + (8 << 20));     // 16 MB  B fragment-major
    ushort*   WgtF  = (ushort*)(wsb + (24 << 20));    //  2 MB  weights frag-major
    ushort*   encF  = (ushort*)(wsb + (26 << 20));    //  1 MB  enc B-frag-major
    float* out_tail = out + (size_t)B * S * VOCAB;

    hipLaunchKernelGGL(k_prep,  dim3(S + 2000),       dim3(256), 0, stream,
                       x, embed, Wi, bi, bh, Ew, Wo, WoTF);
    hipLaunchKernelGGL(k_rnn,   dim3(1),              dim3(512), 0, stream, Ew, Wh, enc16, out_tail);
    hipLaunchKernelGGL(k_qk,    dim3(B * S / 8),      dim3(256), 0, stream, enc16, Wa, ba, q, kT, encF);
    hipLaunchKernelGGL(k_attn,  dim3(B * S),          dim3(256), 0, stream, q, kT, va, WgtF);
    hipLaunchKernelGGL(k_ctx,   dim3(S / 32, B),      dim3(256), 0, stream, WgtF, encF, enc16, AbfF);
    hipLaunchKernelGGL(k_out,   dim3(16, VOCAB / 128), dim3(256), 0, stream, AbfF, WoTF, bo, out);
}

// Round 13
// 576.120 us; speedup vs baseline: 1.0385x; 1.0385x over previous
//
#include <hip/hip_runtime.h>
#include <hip/hip_bf16.h>
#include <hip/hip_fp16.h>

#define VOCAB 32000
#define H 256
#define B 4
#define S 512

typedef _Float16 f16x8 __attribute__((ext_vector_type(8)));
typedef short s16x8 __attribute__((ext_vector_type(8)));
typedef float f32x4 __attribute__((ext_vector_type(4)));

__device__ __forceinline__ float tanh_fast(float x) {
    float e = exp2f(x * 2.885390081777927f);   // exp(2x)
    return 1.0f - 2.0f * __builtin_amdgcn_rcpf(e + 1.0f);
}

// Fragment-major index (A-operand view), KK=8 (K=256)
__device__ __forceinline__ size_t fragIdx(int row, int h) {
    return ((size_t)((((row >> 4) * 8 + (h >> 5)) * 64) + ((h >> 3) & 3) * 16 + (row & 15)) << 3)
           + (h & 7);
}

// ---------------------------------------------------------------------------
// K_PREP: blocks 0..511 = eprep; blocks 512..2511 = Wo->WoTF (64n x 64k tiles)
// ---------------------------------------------------------------------------
__global__ __launch_bounds__(256) void k_prep(const int* __restrict__ x,
                                              const float* __restrict__ embed,
                                              const float* __restrict__ Wi,
                                              const float* __restrict__ bi,
                                              const float* __restrict__ bh,
                                              float* __restrict__ Ew,
                                              const float* __restrict__ Wo,
                                              ushort* __restrict__ WoTF) {
    __shared__ float sm[64 * 65 + 8];
    int tid = threadIdx.x;
    if (blockIdx.x < S) {
        float (*es)[H] = (float(*)[H])sm;
        int* xs = (int*)&sm[B * H];
        int t = blockIdx.x, j = tid;
        if (j < B) xs[j] = x[j * S + t];
        __syncthreads();
        for (int b = 0; b < B; ++b) es[b][j] = embed[(size_t)xs[b] * H + j];
        float bias = bi[j] + bh[j];
        float a0 = bias, a1 = bias, a2 = bias, a3 = bias;
        __syncthreads();
        for (int i = 0; i < H; ++i) {
            float w = Wi[i * H + j];
            a0 += es[0][i] * w; a1 += es[1][i] * w;
            a2 += es[2][i] * w; a3 += es[3][i] * w;
        }
        f32x4 v; v[0] = a0; v[1] = a1; v[2] = a2; v[3] = a3;
        *(f32x4*)&Ew[(t * H + j) * 4] = v;
    } else {
        float (*tile)[65] = (float(*)[65])sm;
        int bid2 = blockIdx.x - S;
        int n0 = (bid2 % 500) * 64;
        int k0 = (bid2 / 500) * 64;
        int tx = tid & 63, ty = tid >> 6;
#pragma unroll
        for (int i = 0; i < 16; ++i) {
            int kr = i * 4 + ty;
            tile[kr][tx] = Wo[(size_t)(k0 + kr) * VOCAB + n0 + tx];
        }
        __syncthreads();
#pragma unroll
        for (int r = 0; r < 2; ++r) {
            int lin = tid + 256 * r;
            int ll = lin & 15, lg = (lin >> 4) & 3, kkL = (lin >> 6) & 1, nt = (lin >> 7) & 3;
            int kk = (k0 >> 5) + kkL;
            int n = nt * 16 + ll;
            s16x8 v;
#pragma unroll
            for (int e = 0; e < 8; ++e) {
                __hip_bfloat16 b = __float2bfloat16(tile[kkL * 32 + lg * 8 + e][n]);
                v[e] = *(short*)&b;
            }
            size_t unit = (size_t)(((n0 >> 4) + nt) * 8 + kk) * 64 + lg * 16 + ll;
            *(s16x8*)&WoTF[unit * 8] = v;
        }
    }
}

// ---------------------------------------------------------------------------
// K2: serial RNN scan, 8 waves / 2 per SIMD (R12: 313us, −2.5% vs 4-wave).
// PARKED after 7 experiments. lg 0-1 -> LDS write; lg 2-3 -> global stores.
// ---------------------------------------------------------------------------
__global__ __launch_bounds__(512, 1) void k_rnn(const float* __restrict__ Ew,
                                                const float* __restrict__ Wh,
                                                _Float16* __restrict__ enc16,
                                                float* __restrict__ out_tail) {
    const int tid = threadIdx.x;
    const int w = tid >> 6;
    const int l = tid & 63;
    const int lg = l >> 4;
    const int ll = l & 15;

    __shared__ _Float16 hbuf[2][4][258];
    for (int idx = tid; idx < 2 * 4 * 258; idx += 512) (&hbuf[0][0][0])[idx] = (_Float16)0.f;

    f16x8 Bf[2][8];
#pragma unroll
    for (int nt = 0; nt < 2; ++nt) {
        int col = w * 32 + nt * 16 + ll;
#pragma unroll
        for (int kk = 0; kk < 8; ++kk) {
            int kb = kk * 32 + lg * 8;
            f16x8 v;
#pragma unroll
            for (int e = 0; e < 8; ++e) v[e] = (_Float16)Wh[(kb + e) * H + col];
            Bf[nt][kk] = v;
        }
    }
    __syncthreads();

    f32x4 eacc[2][2];
#pragma unroll
    for (int d = 0; d < 2; ++d)
#pragma unroll
        for (int nt = 0; nt < 2; ++nt) {
            int j = w * 32 + nt * 16 + ll;
            eacc[d][nt] = *(const f32x4*)&Ew[(d * H + j) * 4];
        }

    const int jcol = w * 32 + (lg & 1) * 16 + ll;

    for (int t0 = 0; t0 < S; t0 += 2) {
#pragma unroll
        for (int u = 0; u < 2; ++u) {
            const int t = t0 + u;
            const int cur = u, nxt = u ^ 1;

            f16x8 Af[8];
#pragma unroll
            for (int kk = 0; kk < 8; ++kk)
                Af[kk] = *(const f16x8*)&hbuf[cur][l & 3][kk * 32 + lg * 8];

            f32x4 acc[2];
#pragma unroll
            for (int nt = 0; nt < 2; ++nt) acc[nt] = eacc[u][nt];

            {
                int tp = (t + 2 < S) ? t + 2 : S - 1;
#pragma unroll
                for (int nt = 0; nt < 2; ++nt) {
                    int j = w * 32 + nt * 16 + ll;
                    eacc[u][nt] = *(const f32x4*)&Ew[(tp * H + j) * 4];
                }
            }

#pragma unroll
            for (int kk = 0; kk < 8; ++kk)
#pragma unroll
                for (int nt = 0; nt < 2; ++nt)
                    acc[nt] = __builtin_amdgcn_mfma_f32_16x16x32_f16(Af[kk], Bf[nt][kk], acc[nt], 0, 0, 0);

            float v[4];
#pragma unroll
            for (int r = 0; r < 4; ++r) v[r] = (lg & 1) ? acc[1][r] : acc[0][r];

            _Float16 h16[4];
#pragma unroll
            for (int r = 0; r < 4; ++r) h16[r] = (_Float16)tanh_fast(v[r]);

            if (lg < 2) {
#pragma unroll
                for (int r = 0; r < 4; ++r) hbuf[nxt][r][jcol] = h16[r];
                if (t == S - 1) {
#pragma unroll
                    for (int r = 0; r < 4; ++r) out_tail[r * H + jcol] = (float)h16[r];
                }
            } else {
#pragma unroll
                for (int r = 0; r < 4; ++r)
                    enc16[(r * S + t) * H + jcol] = h16[r];   // fire-and-forget
            }

            asm volatile("s_waitcnt lgkmcnt(0)" ::: "memory");
            __builtin_amdgcn_s_barrier();
            asm volatile("" ::: "memory");
        }
    }
}

// ---------------------------------------------------------------------------
// K3: q = enc@Wq ; kT = enc@Wk + ba ([b][h][s]); also emits encF (B-frag f16)
// ---------------------------------------------------------------------------
__global__ void k_qk(const _Float16* __restrict__ enc16, const float* __restrict__ Wa,
                     const float* __restrict__ ba, float* __restrict__ q,
                     float* __restrict__ kT, ushort* __restrict__ encF) {
    int r0 = blockIdx.x * 8;
    int j = threadIdx.x;
    __shared__ float es[8][H];
#pragma unroll
    for (int r = 0; r < 8; ++r) es[r][j] = (float)enc16[(r0 + r) * H + j];
    __syncthreads();
    float aq[8] = {0, 0, 0, 0, 0, 0, 0, 0};
    float ak[8] = {0, 0, 0, 0, 0, 0, 0, 0};
    for (int i = 0; i < H; ++i) {
        float wq = Wa[i * H + j];
        float wk = Wa[(H + i) * H + j];
#pragma unroll
        for (int r = 0; r < 8; ++r) { aq[r] += es[r][i] * wq; ak[r] += es[r][i] * wk; }
    }
    float bav = ba[j];
#pragma unroll
    for (int r = 0; r < 8; ++r) {
        int row = r0 + r;
        int b = row >> 9, t = row & (S - 1);
        q[row * H + j] = aq[r];
        kT[((b * H + j) << 9) + t] = ak[r] + bav;
        _Float16 ev = (_Float16)es[r][j];
        size_t unit = (size_t)((b * 16 + (j >> 4)) * 16 + (t >> 5)) * 64 + ((t >> 3) & 3) * 16 + (j & 15);
        encF[unit * 8 + (t & 7)] = *(ushort*)&ev;
    }
}

// ---------------------------------------------------------------------------
// K4: scores -> fixed-max softmax -> normalized f16 weights, A-frag-major.
// ---------------------------------------------------------------------------
__global__ void k_attn(const float* __restrict__ q, const float* __restrict__ kT,
                       const float* __restrict__ va, ushort* __restrict__ WgtF) {
    int bt = blockIdx.x;
    int b = bt >> 9, t = bt & (S - 1);
    int tid = threadIdx.x;
    if (t == 0) {
        for (int ss = tid; ss < S; ss += 256) {
            _Float16 hw = (_Float16)((ss == 0) ? 1.f : 0.f);
            size_t unit = (size_t)((b * 32 + (t >> 4)) * 16 + (ss >> 5)) * 64 + ((ss >> 3) & 3) * 16 + (t & 15);
            WgtF[unit * 8 + (ss & 7)] = *(ushort*)&hw;
        }
        return;
    }
    __shared__ float qs[H], vas[H], part[4][S], wgt[S], red[4];
    qs[tid] = q[bt * H + tid];
    vas[tid] = va[tid];
    __syncthreads();

    int sl = tid & 63, g = tid >> 6;
    int nchunk = (t + 63) >> 6;
    const float* kTb = kT + ((size_t)(b * H) << 9);
    for (int c = 0; c < nchunk; ++c) {
        int s = c * 64 + sl;
        float p = 0.f;
        if (s < t) {
            int hb = g * 64;
            for (int i = 0; i < 64; ++i) {
                int h = hb + i;
                p += vas[h] * tanh_fast(qs[h] + kTb[(h << 9) + s]);
            }
        }
        part[g][s] = p;
    }
    __syncthreads();

    float ssum = 0.f;
    for (int s = tid; s < t; s += 256) {
        float sc = part[0][s] + part[1][s] + part[2][s] + part[3][s];
        float e = exp2f((sc - 16.0f) * 1.4426950408889634f);
        wgt[s] = e;
        ssum += e;
    }
#pragma unroll
    for (int off = 32; off; off >>= 1) ssum += __shfl_xor(ssum, off);
    if ((tid & 63) == 0) red[g] = ssum;
    __syncthreads();
    float inv = 1.0f / (red[0] + red[1] + red[2] + red[3]);

    for (int ss = tid; ss < S; ss += 256) {
        float wv = (ss < t) ? wgt[ss] * inv : 0.f;
        _Float16 hw = (_Float16)wv;
        size_t unit = (size_t)((b * 32 + (t >> 4)) * 16 + (ss >> 5)) * 64 + ((ss >> 3) & 3) * 16 + (t & 15);
        WgtF[unit * 8 + (ss & 7)] = *(ushort*)&hw;
    }
}

// ---------------------------------------------------------------------------
// K_CTX: ctx = Wgt @ enc per batch (MFMA), + enc, -> AbfF fragment-major.
// ---------------------------------------------------------------------------
__global__ __launch_bounds__(256) void k_ctx(const ushort* __restrict__ WgtF,
                                             const ushort* __restrict__ encF,
                                             const _Float16* __restrict__ enc16,
                                             ushort* __restrict__ AbfF) {
    int b = blockIdx.y;
    int m0 = blockIdx.x * 32;
    int tid = threadIdx.x;
    int wv = tid >> 6, l = tid & 63;
    int lg = l >> 4, ll = l & 15;

    f32x4 acc[2][4];
#pragma unroll
    for (int mt = 0; mt < 2; ++mt)
#pragma unroll
        for (int nt = 0; nt < 4; ++nt) { f32x4 z; z[0]=0.f; z[1]=0.f; z[2]=0.f; z[3]=0.f; acc[mt][nt] = z; }

#pragma unroll
    for (int kk = 0; kk < 16; ++kk) {
        f16x8 a[2], bf[4];
#pragma unroll
        for (int mt = 0; mt < 2; ++mt)
            a[mt] = *(const f16x8*)&WgtF[((size_t)((b * 32 + (m0 >> 4) + mt) * 16 + kk) * 64 + l) * 8];
#pragma unroll
        for (int nt = 0; nt < 4; ++nt)
            bf[nt] = *(const f16x8*)&encF[((size_t)((b * 16 + wv * 4 + nt) * 16 + kk) * 64 + l) * 8];
#pragma unroll
        for (int mt = 0; mt < 2; ++mt)
#pragma unroll
            for (int nt = 0; nt < 4; ++nt)
                acc[mt][nt] = __builtin_amdgcn_mfma_f32_16x16x32_f16(a[mt], bf[nt], acc[mt][nt], 0, 0, 0);
    }

#pragma unroll
    for (int mt = 0; mt < 2; ++mt)
#pragma unroll
        for (int nt = 0; nt < 4; ++nt)
#pragma unroll
            for (int r = 0; r < 4; ++r) {
                int trow = m0 + mt * 16 + lg * 4 + r;
                int h = wv * 64 + nt * 16 + ll;
                float ev = (float)enc16[(size_t)(b * S + trow) * H + h];
                __hip_bfloat16 o = __float2bfloat16(acc[mt][nt][r] + ev);
                AbfF[fragIdx(b * S + trow, h)] = *(ushort*)&o;
            }
}

// ---------------------------------------------------------------------------
// K5: out = A @ WoT^T + bo. Fragment-major operands; m-fastest grid.
// v3: LDS-transposed epilogue. Old stores: 64 instrs/wave-chunk, each writing
// 4 scattered rows x 64B segments. New: stage 16x64 f32 per wave in LDS
// (pad 66 -> 2-way conflicts only, free), read back row-major as f32x4 ->
// 16 dwordx4 instrs, 4 rows x 256B segments each. Wave-private region,
// in-order DS per wave -> no barriers.
// ---------------------------------------------------------------------------
__global__ __launch_bounds__(256) void k_out(const ushort* __restrict__ AbfF,
                                             const ushort* __restrict__ WoTF,
                                             const float* __restrict__ bo,
                                             float* __restrict__ out) {
    int tid = threadIdx.x;
    int wv = tid >> 6, l = tid & 63;
    int mw = wv >> 1, nw = wv & 1;
    int lg = l >> 4, ll = l & 15;
    int m0 = blockIdx.x * 128 + mw * 64;
    int n0 = blockIdx.y * 128 + nw * 64;

    __shared__ float st[4][16][66];

    f32x4 acc[4][4];
#pragma unroll
    for (int mt = 0; mt < 4; ++mt)
#pragma unroll
        for (int nt = 0; nt < 4; ++nt) { f32x4 z; z[0]=0.f; z[1]=0.f; z[2]=0.f; z[3]=0.f; acc[mt][nt] = z; }

#pragma unroll
    for (int kk = 0; kk < 8; ++kk) {
        s16x8 a[4], bf[4];
#pragma unroll
        for (int mt = 0; mt < 4; ++mt)
            a[mt] = *(const s16x8*)&AbfF[((size_t)(((m0 >> 4) + mt) * 8 + kk) * 64 + l) * 8];
#pragma unroll
        for (int nt = 0; nt < 4; ++nt)
            bf[nt] = *(const s16x8*)&WoTF[((size_t)(((n0 >> 4) + nt) * 8 + kk) * 64 + l) * 8];
#pragma unroll
        for (int mt = 0; mt < 4; ++mt)
#pragma unroll
            for (int nt = 0; nt < 4; ++nt)
                acc[mt][nt] = __builtin_amdgcn_mfma_f32_16x16x32_bf16(a[mt], bf[nt], acc[mt][nt], 0, 0, 0);
    }

    float bovv[4];
#pragma unroll
    for (int nt = 0; nt < 4; ++nt) bovv[nt] = bo[n0 + nt * 16 + ll];

#pragma unroll
    for (int mt = 0; mt < 4; ++mt) {
        // stage this wave's 16 rows x 64 cols (bias added here)
#pragma unroll
        for (int nt = 0; nt < 4; ++nt)
#pragma unroll
            for (int r = 0; r < 4; ++r)
                st[wv][lg * 4 + r][nt * 16 + ll] = acc[mt][nt][r] + bovv[nt];
        // read back row-major, store contiguous f32x4 (compiler inserts lgkmcnt)
#pragma unroll
        for (int pass = 0; pass < 4; ++pass) {
            int row = pass * 4 + (l >> 4);
            int nq = (l & 15) * 4;
            f32x4 vrow = *(const f32x4*)&st[wv][row][nq];
            int mrow = m0 + mt * 16 + row;
            *(f32x4*)&out[(size_t)mrow * VOCAB + n0 + nq] = vrow;
        }
    }
}

// ---------------------------------------------------------------------------
extern "C" void kernel_launch(void* const* d_in, const int* in_sizes, int n_in,
                              void* d_out, int out_size, void* d_ws, size_t ws_size,
                              hipStream_t stream) {
    const int*   x     = (const int*)d_in[0];
    const float* embed = (const float*)d_in[1];
    const float* Wi    = (const float*)d_in[2];
    const float* bi    = (const float*)d_in[3];
    const float* Wh    = (const float*)d_in[4];
    const float* bh    = (const float*)d_in[5];
    const float* Wa    = (const float*)d_in[6];
    const float* ba    = (const float*)d_in[7];
    const float* va    = (const float*)d_in[8];
    const float* Wo    = (const float*)d_in[9];
    const float* bo    = (const float*)d_in[10];
    float* out = (float*)d_out;

    char* wsb = (char*)d_ws;
    float*    Ew    = (float*)(wsb);                  //  2 MB
    _Float16* enc16 = (_Float16*)(wsb + (2 << 20));   //  1 MB
    float*    q     = (float*)(wsb + (3 << 20));      //  2 MB
    float*    kT    = (float*)(wsb + (5 << 20));      //  2 MB
    ushort*   AbfF  = (ushort*)(wsb + (7 << 20));     //  1 MB  A fragment-major
    ushort*   WoTF  = (ushort*)(wsb + (8 << 20));     // 16 MB  B fragment-major
    ushort*   WgtF  = (ushort*)(wsb + (24 << 20));    //  2 MB  weights frag-major
    ushort*   encF  = (ushort*)(wsb + (26 << 20));    //  1 MB  enc B-frag-major
    float* out_tail = out + (size_t)B * S * VOCAB;

    hipLaunchKernelGGL(k_prep,  dim3(S + 2000),       dim3(256), 0, stream,
                       x, embed, Wi, bi, bh, Ew, Wo, WoTF);
    hipLaunchKernelGGL(k_rnn,   dim3(1),              dim3(512), 0, stream, Ew, Wh, enc16, out_tail);
    hipLaunchKernelGGL(k_qk,    dim3(B * S / 8),      dim3(256), 0, stream, enc16, Wa, ba, q, kT, encF);
    hipLaunchKernelGGL(k_attn,  dim3(B * S),          dim3(256), 0, stream, q, kT, va, WgtF);
    hipLaunchKernelGGL(k_ctx,   dim3(S / 32, B),      dim3(256), 0, stream, WgtF, encF, enc16, AbfF);
    hipLaunchKernelGGL(k_out,   dim3(16, VOCAB / 128), dim3(256), 0, stream, AbfF, WoTF, bo, out);
}